// Round 3
// baseline (484.446 us; speedup 1.0000x reference)
//
#include <hip/hip_runtime.h>
#include <math.h>

#define NSEG 8192
#define D 32
#define EPSF 1e-10f
#define BLK 256
#define SEG_PER_BLK 4   // one wave per segment, 4 waves per block

// ---------------------------------------------------------------------------
// seg_start[s] = first row index i with batch[i] >= s  (batch is sorted).
// seg_start has NSEG+1 entries; seg_start[NSEG] = N. Lives in d_ws.
// ---------------------------------------------------------------------------
__global__ void init_starts_kernel(int* __restrict__ seg_start, int N) {
    int s = blockIdx.x * blockDim.x + threadIdx.x;
    if (s <= NSEG) seg_start[s] = N;   // default: empty tail segments
}

__global__ void find_starts_kernel(const int* __restrict__ batch,
                                   int* __restrict__ seg_start, int N) {
    int i = blockIdx.x * blockDim.x + threadIdx.x;
    if (i >= N) return;
    int b = batch[i];
    int prev = (i == 0) ? -1 : batch[i - 1];
    // almost always 0 or 1 iterations (segments are dense)
    for (int s = prev + 1; s <= b; ++s) seg_start[s] = i;
}

// ---------------------------------------------------------------------------
// float4 helpers
// ---------------------------------------------------------------------------
__device__ __forceinline__ float4 f4max(float4 a, float4 b) {
    return make_float4(fmaxf(a.x, b.x), fmaxf(a.y, b.y),
                       fmaxf(a.z, b.z), fmaxf(a.w, b.w));
}
__device__ __forceinline__ float4 shfl_xor_f4(float4 v, int mask) {
    return make_float4(__shfl_xor(v.x, mask, 64), __shfl_xor(v.y, mask, 64),
                       __shfl_xor(v.z, mask, 64), __shfl_xor(v.w, mask, 64));
}

// ---------------------------------------------------------------------------
// One WAVE per segment; no LDS, no __syncthreads, shuffle-only reduction.
// Lane layout: cg = lane&7 -> 4 columns (float4), rg = lane>>3 -> rows
// rg, rg+8, ... Wave's 64 lanes cover 8 consecutive rows x 32 cols = 1 KB
// contiguous per vector load instruction (perfect coalescing).
//
// Pass 1: online softmax (running max m, rescaled sum l) -> x read once (HBM).
// Butterfly merge of (m,l) across rg via shfl_xor 8/16/32.
// Pass 2: out = exp(x - m) / (l + eps) -> x re-read (L1/L2/L3 warm).
// m initialized to -FLT_MAX (not -inf) so lanes with no rows (len<8) cannot
// create exp(-inf - -inf) = NaN in the merge.
// ---------------------------------------------------------------------------
__global__ __launch_bounds__(BLK, 8) void seg_softmax_kernel(
    const float* __restrict__ x, const int* __restrict__ seg_start,
    float* __restrict__ out)
{
    const int wave = (int)threadIdx.x >> 6;
    const int lane = (int)threadIdx.x & 63;
    const int s    = blockIdx.x * SEG_PER_BLK + wave;

    const int start = seg_start[s];
    const int len   = seg_start[s + 1] - start;
    if (len <= 0) return;   // empty segment: nothing to write

    const int cg = lane & 7;     // col group (4 floats)
    const int rg = lane >> 3;    // row group 0..7, stride 8

    const float4* __restrict__ xin  = (const float4*)(x   + (size_t)start * D);
    float4* __restrict__       outv = (float4*)      (out + (size_t)start * D);

    // ---- pass 1: online max+sum over this lane's rows ----
    float4 m = make_float4(-3.402823466e38f, -3.402823466e38f,
                           -3.402823466e38f, -3.402823466e38f);
    float4 l = make_float4(0.f, 0.f, 0.f, 0.f);
    for (int r = rg; r < len; r += 8) {
        float4 v = xin[r * 8 + cg];
        float4 mn = f4max(m, v);
        l.x = l.x * __expf(m.x - mn.x) + __expf(v.x - mn.x);
        l.y = l.y * __expf(m.y - mn.y) + __expf(v.y - mn.y);
        l.z = l.z * __expf(m.z - mn.z) + __expf(v.z - mn.z);
        l.w = l.w * __expf(m.w - mn.w) + __expf(v.w - mn.w);
        m = mn;
    }

    // ---- butterfly merge across the 8 row-groups (lanes with same cg) ----
    #pragma unroll
    for (int mask = 8; mask <= 32; mask <<= 1) {
        float4 mo = shfl_xor_f4(m, mask);
        float4 lo = shfl_xor_f4(l, mask);
        float4 mn = f4max(m, mo);
        l.x = l.x * __expf(m.x - mn.x) + lo.x * __expf(mo.x - mn.x);
        l.y = l.y * __expf(m.y - mn.y) + lo.y * __expf(mo.y - mn.y);
        l.z = l.z * __expf(m.z - mn.z) + lo.z * __expf(mo.z - mn.z);
        l.w = l.w * __expf(m.w - mn.w) + lo.w * __expf(mo.w - mn.w);
        m = mn;
    }

    const float4 rn = make_float4(1.f / (l.x + EPSF), 1.f / (l.y + EPSF),
                                  1.f / (l.z + EPSF), 1.f / (l.w + EPSF));

    // ---- pass 2: normalize + store (re-read is cache-warm) ----
    for (int r = rg; r < len; r += 8) {
        float4 v = xin[r * 8 + cg];
        float4 e;
        e.x = __expf(v.x - m.x) * rn.x;
        e.y = __expf(v.y - m.y) * rn.y;
        e.z = __expf(v.z - m.z) * rn.z;
        e.w = __expf(v.w - m.w) * rn.w;
        outv[r * 8 + cg] = e;
    }
}

// ---------------------------------------------------------------------------
extern "C" void kernel_launch(void* const* d_in, const int* in_sizes, int n_in,
                              void* d_out, int out_size, void* d_ws, size_t ws_size,
                              hipStream_t stream) {
    const int*   batch = (const int*)d_in[0];
    const float* x     = (const float*)d_in[1];
    float*       out   = (float*)d_out;
    const int    N     = in_sizes[0];

    int* seg_start = (int*)d_ws;   // (NSEG+1) ints; re-initialized every call

    init_starts_kernel<<<(NSEG + 1 + 255) / 256, 256, 0, stream>>>(seg_start, N);
    find_starts_kernel<<<(N + 255) / 256, 256, 0, stream>>>(batch, seg_start, N);
    seg_softmax_kernel<<<NSEG / SEG_PER_BLK, BLK, 0, stream>>>(x, seg_start, out);
}